// Round 1
// baseline (319.942 us; speedup 1.0000x reference)
//
#include <hip/hip_runtime.h>

typedef unsigned int u32;
typedef unsigned short u16;
typedef float f4 __attribute__((ext_vector_type(4)));
typedef __bf16 b8 __attribute__((ext_vector_type(8)));
typedef unsigned short us8 __attribute__((ext_vector_type(8)));

#define DD 64
#define NE 16
#define OO 512
#define TR 64
#define MAXT 1344

struct __align__(16) Tile { u32 pid, slot, nr, pad; };

union U8 { us8 u; b8 b; };

__device__ __forceinline__ u16 f2bf(float f) {
  u32 u = __float_as_uint(f);
  u32 r = (u + 0x7fffu + ((u >> 16) & 1u)) >> 16;
  return (u16)r;
}

// ---------------- We [e][d][o] fp32 -> WeT [e][o][d] bf16 ----------------
__global__ void k_wt(const float* __restrict__ We, u16* __restrict__ WeT) {
  __shared__ float tl[64][65];
  int b = blockIdx.x;          // 16 experts * 8 o-chunks
  int e = b >> 3;
  int oc = (b & 7) * 64;
  int t = threadIdx.x;
  int d = t >> 2, seg = (t & 3) * 16;
  const f4* src = (const f4*)(We + ((size_t)(e * DD + d)) * OO + oc + seg);
  f4 v0 = src[0], v1 = src[1], v2 = src[2], v3 = src[3];
#pragma unroll
  for (int j = 0; j < 4; j++) {
    tl[d][seg + j]      = v0[j];
    tl[d][seg + 4 + j]  = v1[j];
    tl[d][seg + 8 + j]  = v2[j];
    tl[d][seg + 12 + j] = v3[j];
  }
  __syncthreads();
  int o = t >> 2, ds = (t & 3) * 16;
  us8 o0, o1;
#pragma unroll
  for (int j = 0; j < 8; j++) {
    o0[j] = f2bf(tl[ds + j][o]);
    o1[j] = f2bf(tl[ds + 8 + j][o]);
  }
  u16* dst = WeT + ((size_t)(e * OO + oc + o)) * DD + ds;
  *(us8*)dst = o0;
  *(us8*)(dst + 8) = o1;
}

// ---------------- gating: logits -> softmax -> top2 -> (pid, g_lo, g_hi) ----------------
__global__ void k_gate(const float* __restrict__ x, const float* __restrict__ wg,
                       const float* __restrict__ bg, u32* __restrict__ cnt,
                       u32* __restrict__ pid_arr, float* __restrict__ glo_arr,
                       float* __restrict__ ghi_arr) {
  __shared__ u32 hcnt[256];
  int t = threadIdx.x;
  hcnt[t] = 0;
  __syncthreads();
  int row = blockIdx.x * 256 + t;

  float l[NE];
#pragma unroll
  for (int e = 0; e < NE; e++) l[e] = bg[e];

  const f4* xp = (const f4*)(x + (size_t)row * DD);
  for (int d4 = 0; d4 < 16; d4++) {
    f4 xv = xp[d4];
#pragma unroll
    for (int qq = 0; qq < 4; qq++) {
      float xs = xv[qq];
      const float* wrow = wg + (d4 * 4 + qq) * NE;
#pragma unroll
      for (int e = 0; e < NE; e++) l[e] = fmaf(xs, wrow[e], l[e]);
    }
  }
  float mx = l[0];
#pragma unroll
  for (int e = 1; e < NE; e++) mx = fmaxf(mx, l[e]);
  float Z = 0.f;
#pragma unroll
  for (int e = 0; e < NE; e++) Z += __expf(l[e] - mx);
  int i1 = 0; float b1 = l[0];
#pragma unroll
  for (int e = 1; e < NE; e++) { if (l[e] > b1) { b1 = l[e]; i1 = e; } }
  int i2 = -1; float b2 = -1e30f;
#pragma unroll
  for (int e = 0; e < NE; e++) { if (e != i1 && l[e] > b2) { b2 = l[e]; i2 = e; } }
  float p1 = __expf(b1 - mx) / Z;
  float p2 = __expf(b2 - mx) / Z;
  float den = p1 + p2 + 1e-6f;   // reference: top_vals / (sum(top_vals) + 1e-6)
  float g1 = p1 / den, g2 = p2 / den;
  int elo, ehi; float glo, ghi;
  if (i1 < i2) { elo = i1; ehi = i2; glo = g1; ghi = g2; }
  else         { elo = i2; ehi = i1; glo = g2; ghi = g1; }
  u32 pid = (u32)(elo * NE + ehi);
  pid_arr[row] = pid;
  glo_arr[row] = glo;
  ghi_arr[row] = ghi;
  atomicAdd(&hcnt[pid], 1u);
  __syncthreads();
  u32 c = hcnt[t];
  if (c) atomicAdd(&cnt[t], c);
}

// ---------------- scan counts -> offsets/cursor + tile descriptors ----------------
__global__ void k_scan(const u32* __restrict__ cnt, u32* __restrict__ cursor,
                       u32* __restrict__ ntp, Tile* __restrict__ tiles) {
  __shared__ u32 s[256], s2[256];
  int t = threadIdx.x;
  u32 v = cnt[t];
  u32 nt = (v + (TR - 1)) >> 6;
  s[t] = v; s2[t] = nt;
  __syncthreads();
  for (int d = 1; d < 256; d <<= 1) {
    u32 a = 0, b = 0;
    if (t >= d) { a = s[t - d]; b = s2[t - d]; }
    __syncthreads();
    s[t] += a; s2[t] += b;
    __syncthreads();
  }
  u32 sl0 = s[t] - v;
  u32 tb  = s2[t] - nt;
  cursor[t] = sl0;
  for (u32 k = 0; k < nt; k++) {
    Tile td;
    td.pid = (u32)t;
    td.slot = sl0 + k * (u32)TR;
    u32 rem = v - k * (u32)TR;
    td.nr = rem < (u32)TR ? rem : (u32)TR;
    td.pad = 0;
    tiles[tb + k] = td;
  }
  if (t == 255) *ntp = s2[255];
}

// ---------------- scatter rows into pair buckets ----------------
__global__ void k_scatter(const u32* __restrict__ pid_arr, u32* __restrict__ cursor,
                          u32* __restrict__ sorted) {
  int row = blockIdx.x * 256 + threadIdx.x;
  u32 pid = pid_arr[row];
  u32 slot = atomicAdd(&cursor[pid], 1u);
  sorted[slot] = (u32)row;
}

// ---------------- main: per pair-tile GEMM (2 experts) + gated combine ----------------
__global__ void k_moe(const float* __restrict__ x, const u16* __restrict__ WeT,
                      const float* __restrict__ be, const u32* __restrict__ sorted,
                      const u32* __restrict__ ntp, const Tile* __restrict__ tiles,
                      const float* __restrict__ glo_arr, const float* __restrict__ ghi_arr,
                      float* __restrict__ y) {
  __shared__ __align__(16) u16 Xl[TR * 72];   // stride 72 (144B) breaks bank conflicts
  __shared__ u32 rid_s[TR];
  __shared__ float glo_s[TR], ghi_s[TR];

  u32 bid = blockIdx.x;
  if (bid >= *ntp) return;
  Tile td = tiles[bid];
  u32 e_lo = td.pid >> 4, e_hi = td.pid & 15u;
  u32 slot0 = td.slot, nr = td.nr;

  int t = threadIdx.x;
  if (t < TR) {
    u32 i = (u32)t;
    u32 slot = slot0 + ((i < nr) ? i : 0u);
    u32 r = sorted[slot];
    rid_s[t] = r;
    bool valid = i < nr;
    glo_s[t] = valid ? glo_arr[r] : 0.f;
    ghi_s[t] = valid ? ghi_arr[r] : 0.f;
  }
  __syncthreads();
  {
    int i = t >> 2;
    int seg = (t & 3) * 16;
    u32 r = rid_s[i];
    const f4* xp = (const f4*)(x + (size_t)r * DD + seg);
    f4 v0 = xp[0], v1 = xp[1], v2 = xp[2], v3 = xp[3];
    float vv[16] = { v0[0], v0[1], v0[2], v0[3], v1[0], v1[1], v1[2], v1[3],
                     v2[0], v2[1], v2[2], v2[3], v3[0], v3[1], v3[2], v3[3] };
    us8 o0, o1;
#pragma unroll
    for (int j = 0; j < 8; j++) { o0[j] = f2bf(vv[j]); o1[j] = f2bf(vv[8 + j]); }
    *(us8*)&Xl[i * 72 + seg] = o0;
    *(us8*)&Xl[i * 72 + seg + 8] = o1;
  }
  __syncthreads();

  int lane = t & 63;
  int w = t >> 6;
  int q = lane >> 4;      // quad
  int ln = lane & 15;

  // A-fragments: A[m][k], m = ln, k = q*8 + j  (per-MFMA K=32 chunk kc)
  b8 afr[4][2];
#pragma unroll
  for (int mt = 0; mt < 4; mt++)
#pragma unroll
    for (int kc = 0; kc < 2; kc++) {
      U8 tmp; tmp.u = *(const us8*)&Xl[(mt * 16 + ln) * 72 + kc * 32 + q * 8];
      afr[mt][kc] = tmp.b;
    }

  // per-lane row metadata for the 16 C rows this lane owns (row = mt*16 + q*4 + rr)
  float gl[16], gh[16]; u32 rb[16];
#pragma unroll
  for (int mt = 0; mt < 4; mt++)
#pragma unroll
    for (int rr = 0; rr < 4; rr++) {
      int i = mt * 16 + q * 4 + rr;
      int idx = mt * 4 + rr;
      gl[idx] = glo_s[i];
      gh[idx] = ghi_s[i];
      rb[idx] = rid_s[i] * (u32)OO;
    }

  const u16* wlo = WeT + (size_t)e_lo * OO * DD;
  const u16* whi = WeT + (size_t)e_hi * OO * DD;
  const f4 zero = {0.f, 0.f, 0.f, 0.f};

  for (int j = 0; j < 8; j++) {
    int n0 = (w * 8 + j) * 16;
    int col = n0 + ln;
    // B-fragments: B[k][n], n = ln, k = q*8 + jj ; WeT row = [o][d] k-contiguous
    const us8* plo = (const us8*)(wlo + (size_t)col * DD + q * 8);
    const us8* phi = (const us8*)(whi + (size_t)col * DD + q * 8);
    U8 t0, t1, t2, t3;
    t0.u = plo[0]; t1.u = plo[4];   // +32 elems = k-chunk 1
    t2.u = phi[0]; t3.u = phi[4];
    b8 bl0 = t0.b, bl1 = t1.b, bh0 = t2.b, bh1 = t3.b;
    float blo = be[e_lo * OO + col];
    float bhi = be[e_hi * OO + col];

    f4 aL[4], aH[4];
#pragma unroll
    for (int mt = 0; mt < 4; mt++) { aL[mt] = zero; aH[mt] = zero; }
#pragma unroll
    for (int mt = 0; mt < 4; mt++) {
      aL[mt] = __builtin_amdgcn_mfma_f32_16x16x32_bf16(afr[mt][0], bl0, aL[mt], 0, 0, 0);
      aL[mt] = __builtin_amdgcn_mfma_f32_16x16x32_bf16(afr[mt][1], bl1, aL[mt], 0, 0, 0);
      aH[mt] = __builtin_amdgcn_mfma_f32_16x16x32_bf16(afr[mt][0], bh0, aH[mt], 0, 0, 0);
      aH[mt] = __builtin_amdgcn_mfma_f32_16x16x32_bf16(afr[mt][1], bh1, aH[mt], 0, 0, 0);
    }
#pragma unroll
    for (int mt = 0; mt < 4; mt++)
#pragma unroll
      for (int rr = 0; rr < 4; rr++) {
        int i = mt * 16 + q * 4 + rr;
        int idx = mt * 4 + rr;
        // y = g_lo*(x@W_lo + b_lo) + g_hi*(x@W_hi + b_hi), expert-index order
        float v = gl[idx] * (aL[mt][rr] + blo) + gh[idx] * (aH[mt][rr] + bhi);
        if ((u32)i < nr) y[(size_t)rb[idx] + col] = v;
      }
  }
}

extern "C" void kernel_launch(void* const* d_in, const int* in_sizes, int n_in,
                              void* d_out, int out_size, void* d_ws, size_t ws_size,
                              hipStream_t stream) {
  const float* x  = (const float*)d_in[0];
  const float* wg = (const float*)d_in[1];
  const float* bg = (const float*)d_in[2];
  const float* We = (const float*)d_in[3];
  const float* be = (const float*)d_in[4];
  float* y = (float*)d_out;

  char* ws = (char*)d_ws;
  u32* cnt     = (u32*)(ws + 0);                      // 256 u32
  u32* cursor  = (u32*)(ws + 1024);                   // 256 u32
  u32* ntp     = (u32*)(ws + 2048);                   // 1 u32
  Tile* tiles  = (Tile*)(ws + 4096);                  // <= 1344 * 16B
  u32* pid_arr = (u32*)(ws + 32768);                  // 65536 u32
  float* glo_a = (float*)(ws + 32768 + 262144);       // 65536 f32
  float* ghi_a = (float*)(ws + 32768 + 2 * 262144);   // 65536 f32
  u32* sorted  = (u32*)(ws + 32768 + 3 * 262144);     // 65536 u32
  u16* WeT     = (u16*)(ws + 32768 + 4 * 262144);     // 524288 bf16 (1MB)

  hipMemsetAsync(cnt, 0, 1024, stream);
  k_wt<<<128, 256, 0, stream>>>(We, WeT);
  k_gate<<<256, 256, 0, stream>>>(x, wg, bg, cnt, pid_arr, glo_a, ghi_a);
  k_scan<<<1, 256, 0, stream>>>(cnt, cursor, ntp, tiles);
  k_scatter<<<256, 256, 0, stream>>>(pid_arr, cursor, sorted);
  k_moe<<<1144, 256, 0, stream>>>(x, WeT, be, sorted, ntp, tiles, glo_a, ghi_a, y);
}

// Round 2
// 217.428 us; speedup vs baseline: 1.4715x; 1.4715x over previous
//
#include <hip/hip_runtime.h>

typedef unsigned int u32;
typedef unsigned short u16;
typedef float f4 __attribute__((ext_vector_type(4)));
typedef __bf16 b8 __attribute__((ext_vector_type(8)));
typedef unsigned short us8 __attribute__((ext_vector_type(8)));

#define DD 64
#define NE 16
#define OO 512
#define TR 64
#define MAXT 1344

struct __align__(16) Tile { u32 pid, slot, nr, pad; };

union U8 { us8 u; b8 b; };

__device__ __forceinline__ u16 f2bf(float f) {
  u32 u = __float_as_uint(f);
  u32 r = (u + 0x7fffu + ((u >> 16) & 1u)) >> 16;
  return (u16)r;
}

// ---------------- We [e][d][o] fp32 -> WeT [e][o][d] bf16 ----------------
__global__ void k_wt(const float* __restrict__ We, u16* __restrict__ WeT) {
  __shared__ float tl[64][65];
  int b = blockIdx.x;          // 16 experts * 8 o-chunks
  int e = b >> 3;
  int oc = (b & 7) * 64;
  int t = threadIdx.x;
  int d = t >> 2, seg = (t & 3) * 16;
  const f4* src = (const f4*)(We + ((size_t)(e * DD + d)) * OO + oc + seg);
  f4 v0 = src[0], v1 = src[1], v2 = src[2], v3 = src[3];
#pragma unroll
  for (int j = 0; j < 4; j++) {
    tl[d][seg + j]      = v0[j];
    tl[d][seg + 4 + j]  = v1[j];
    tl[d][seg + 8 + j]  = v2[j];
    tl[d][seg + 12 + j] = v3[j];
  }
  __syncthreads();
  int o = t >> 2, ds = (t & 3) * 16;
  us8 o0, o1;
#pragma unroll
  for (int j = 0; j < 8; j++) {
    o0[j] = f2bf(tl[ds + j][o]);
    o1[j] = f2bf(tl[ds + 8 + j][o]);
  }
  u16* dst = WeT + ((size_t)(e * OO + oc + o)) * DD + ds;
  *(us8*)dst = o0;
  *(us8*)(dst + 8) = o1;
}

// ---------------- gating: logits -> softmax -> top2; per-block histogram, NO global atomics ----------------
__global__ void k_gate(const float* __restrict__ x, const float* __restrict__ wg,
                       const float* __restrict__ bg, u32* __restrict__ hist,
                       u32* __restrict__ pid_arr, float* __restrict__ glo_arr,
                       float* __restrict__ ghi_arr) {
  __shared__ u32 hcnt[256];
  int t = threadIdx.x;
  hcnt[t] = 0;
  __syncthreads();
  int row = blockIdx.x * 256 + t;

  float l[NE];
#pragma unroll
  for (int e = 0; e < NE; e++) l[e] = bg[e];

  const f4* xp = (const f4*)(x + (size_t)row * DD);
  for (int d4 = 0; d4 < 16; d4++) {
    f4 xv = xp[d4];
#pragma unroll
    for (int qq = 0; qq < 4; qq++) {
      float xs = xv[qq];
      const float* wrow = wg + (d4 * 4 + qq) * NE;
#pragma unroll
      for (int e = 0; e < NE; e++) l[e] = fmaf(xs, wrow[e], l[e]);
    }
  }
  float mx = l[0];
#pragma unroll
  for (int e = 1; e < NE; e++) mx = fmaxf(mx, l[e]);
  float Z = 0.f;
#pragma unroll
  for (int e = 0; e < NE; e++) Z += __expf(l[e] - mx);
  int i1 = 0; float b1 = l[0];
#pragma unroll
  for (int e = 1; e < NE; e++) { if (l[e] > b1) { b1 = l[e]; i1 = e; } }
  int i2 = -1; float b2 = -1e30f;
#pragma unroll
  for (int e = 0; e < NE; e++) { if (e != i1 && l[e] > b2) { b2 = l[e]; i2 = e; } }
  float p1 = __expf(b1 - mx) / Z;
  float p2 = __expf(b2 - mx) / Z;
  float den = p1 + p2 + 1e-6f;   // reference: top_vals / (sum(top_vals) + 1e-6)
  float g1 = p1 / den, g2 = p2 / den;
  int elo, ehi; float glo, ghi;
  if (i1 < i2) { elo = i1; ehi = i2; glo = g1; ghi = g2; }
  else         { elo = i2; ehi = i1; glo = g2; ghi = g1; }
  u32 pid = (u32)(elo * NE + ehi);
  pid_arr[row] = pid;
  glo_arr[row] = glo;
  ghi_arr[row] = ghi;
  atomicAdd(&hcnt[pid], 1u);   // LDS atomic only
  __syncthreads();
  hist[blockIdx.x * 256 + t] = hcnt[t];   // coalesced, no global atomics
}

// ---------------- scan: hist[block][pid] -> global exclusive offsets + tiles ----------------
__global__ void k_scan(u32* __restrict__ hist, u32* __restrict__ ntp,
                       Tile* __restrict__ tiles) {
  __shared__ u32 s[256], s2[256];
  int t = threadIdx.x;
  u32 total = 0;
  for (int b = 0; b < 256; b++) total += hist[b * 256 + t];   // coalesced
  u32 nt = (total + (TR - 1)) >> 6;
  s[t] = total; s2[t] = nt;
  __syncthreads();
  for (int d = 1; d < 256; d <<= 1) {
    u32 a = 0, c = 0;
    if (t >= d) { a = s[t - d]; c = s2[t - d]; }
    __syncthreads();
    s[t] += a; s2[t] += c;
    __syncthreads();
  }
  u32 base = s[t] - total;   // exclusive row base for pid t
  u32 tb   = s2[t] - nt;     // tile base for pid t
  // rewrite hist[b][t] to the global exclusive slot offset for (block b, pid t)
  u32 run = base;
  for (int b = 0; b < 256; b++) {
    u32 v = hist[b * 256 + t];
    hist[b * 256 + t] = run;
    run += v;
  }
  for (u32 k = 0; k < nt; k++) {
    Tile td;
    td.pid = (u32)t;
    td.slot = base + k * (u32)TR;
    u32 rem = total - k * (u32)TR;
    td.nr = rem < (u32)TR ? rem : (u32)TR;
    td.pad = 0;
    tiles[tb + k] = td;
  }
  if (t == 255) *ntp = s2[255];
}

// ---------------- scatter rows into pair buckets (LDS atomics only) ----------------
__global__ void k_scatter(const u32* __restrict__ pid_arr, const u32* __restrict__ hist,
                          u32* __restrict__ sorted) {
  __shared__ u32 lcnt[256];
  int t = threadIdx.x;
  lcnt[t] = 0;
  __syncthreads();
  int row = blockIdx.x * 256 + t;
  u32 pid = pid_arr[row];
  u32 rank = atomicAdd(&lcnt[pid], 1u);
  u32 off = hist[blockIdx.x * 256 + pid];
  sorted[off + rank] = (u32)row;
}

// ---------------- main: per pair-tile GEMM (2 experts) + gated combine ----------------
__global__ void k_moe(const float* __restrict__ x, const u16* __restrict__ WeT,
                      const float* __restrict__ be, const u32* __restrict__ sorted,
                      const u32* __restrict__ ntp, const Tile* __restrict__ tiles,
                      const float* __restrict__ glo_arr, const float* __restrict__ ghi_arr,
                      float* __restrict__ y) {
  __shared__ __align__(16) u16 Xl[TR * 72];     // 9.2 KB, stride 72 breaks conflicts
  __shared__ __align__(16) float Yl[TR * 68];   // 17 KB, stride 68 -> 2-way (free)
  __shared__ u32 rid_s[TR];
  __shared__ float glo_s[TR], ghi_s[TR];

  u32 bid = blockIdx.x;
  if (bid >= *ntp) return;
  Tile td = tiles[bid];
  u32 e_lo = td.pid >> 4, e_hi = td.pid & 15u;
  u32 slot0 = td.slot, nr = td.nr;

  int t = threadIdx.x;
  if (t < TR) {
    u32 i = (u32)t;
    u32 slot = slot0 + ((i < nr) ? i : 0u);
    u32 r = sorted[slot];
    rid_s[t] = r;
    bool valid = i < nr;
    glo_s[t] = valid ? glo_arr[r] : 0.f;
    ghi_s[t] = valid ? ghi_arr[r] : 0.f;
  }
  __syncthreads();
  {
    int i = t >> 2;
    int seg = (t & 3) * 16;
    u32 r = rid_s[i];
    const f4* xp = (const f4*)(x + (size_t)r * DD + seg);
    f4 v0 = xp[0], v1 = xp[1], v2 = xp[2], v3 = xp[3];
    float vv[16] = { v0[0], v0[1], v0[2], v0[3], v1[0], v1[1], v1[2], v1[3],
                     v2[0], v2[1], v2[2], v2[3], v3[0], v3[1], v3[2], v3[3] };
    us8 o0, o1;
#pragma unroll
    for (int j = 0; j < 8; j++) { o0[j] = f2bf(vv[j]); o1[j] = f2bf(vv[8 + j]); }
    *(us8*)&Xl[i * 72 + seg] = o0;
    *(us8*)&Xl[i * 72 + seg + 8] = o1;
  }
  __syncthreads();

  int lane = t & 63;
  int w = t >> 6;
  int q = lane >> 4;      // quad
  int ln = lane & 15;

  // A-fragments: A[m][k], m = ln, k = q*8 + j  (per-MFMA K=32 chunk kc)
  b8 afr[4][2];
#pragma unroll
  for (int mt = 0; mt < 4; mt++)
#pragma unroll
    for (int kc = 0; kc < 2; kc++) {
      U8 tmp; tmp.u = *(const us8*)&Xl[(mt * 16 + ln) * 72 + kc * 32 + q * 8];
      afr[mt][kc] = tmp.b;
    }

  // per-lane gate metadata for the 16 C rows this lane owns (row = mt*16 + q*4 + rr)
  float gl[16], gh[16];
#pragma unroll
  for (int mt = 0; mt < 4; mt++)
#pragma unroll
    for (int rr = 0; rr < 4; rr++) {
      int i = mt * 16 + q * 4 + rr;
      gl[mt * 4 + rr] = glo_s[i];
      gh[mt * 4 + rr] = ghi_s[i];
    }

  const u16* wlo = WeT + (size_t)e_lo * OO * DD;
  const u16* whi = WeT + (size_t)e_hi * OO * DD;
  const f4 zero = {0.f, 0.f, 0.f, 0.f};

  // per jj the block produces one contiguous 64-col stripe: cols [jj*64, jj*64+64)
  for (int jj = 0; jj < 8; jj++) {
    int col = jj * 64 + w * 16 + ln;
    const us8* plo = (const us8*)(wlo + (size_t)col * DD + q * 8);
    const us8* phi = (const us8*)(whi + (size_t)col * DD + q * 8);
    U8 t0, t1, t2, t3;
    t0.u = plo[0]; t1.u = plo[4];   // +32 elems = k-chunk 1
    t2.u = phi[0]; t3.u = phi[4];
    b8 bl0 = t0.b, bl1 = t1.b, bh0 = t2.b, bh1 = t3.b;
    float blo = be[e_lo * OO + col];
    float bhi = be[e_hi * OO + col];

    f4 aL[4], aH[4];
#pragma unroll
    for (int mt = 0; mt < 4; mt++) { aL[mt] = zero; aH[mt] = zero; }
#pragma unroll
    for (int mt = 0; mt < 4; mt++) {
      aL[mt] = __builtin_amdgcn_mfma_f32_16x16x32_bf16(afr[mt][0], bl0, aL[mt], 0, 0, 0);
      aL[mt] = __builtin_amdgcn_mfma_f32_16x16x32_bf16(afr[mt][1], bl1, aL[mt], 0, 0, 0);
      aH[mt] = __builtin_amdgcn_mfma_f32_16x16x32_bf16(afr[mt][0], bh0, aH[mt], 0, 0, 0);
      aH[mt] = __builtin_amdgcn_mfma_f32_16x16x32_bf16(afr[mt][1], bh1, aH[mt], 0, 0, 0);
    }
    // gated combine into the LDS stripe
#pragma unroll
    for (int mt = 0; mt < 4; mt++)
#pragma unroll
      for (int rr = 0; rr < 4; rr++) {
        int i = mt * 16 + q * 4 + rr;
        int idx = mt * 4 + rr;
        float v = gl[idx] * (aL[mt][rr] + blo) + gh[idx] * (aH[mt][rr] + bhi);
        Yl[i * 68 + w * 16 + ln] = v;
      }
    __syncthreads();
    // cooperative store: 4 lanes per row write 256B contiguous -> full 128B lines
    {
      int row = t >> 2;
      int cs = (t & 3) * 16;
      if ((u32)row < nr) {
        float* yp = y + (size_t)rid_s[row] * OO + jj * 64 + cs;
        const float* sp = &Yl[row * 68 + cs];
#pragma unroll
        for (int u2 = 0; u2 < 4; u2++)
          *(f4*)(yp + u2 * 4) = *(const f4*)(sp + u2 * 4);
      }
    }
    __syncthreads();
  }
}

extern "C" void kernel_launch(void* const* d_in, const int* in_sizes, int n_in,
                              void* d_out, int out_size, void* d_ws, size_t ws_size,
                              hipStream_t stream) {
  const float* x  = (const float*)d_in[0];
  const float* wg = (const float*)d_in[1];
  const float* bg = (const float*)d_in[2];
  const float* We = (const float*)d_in[3];
  const float* be = (const float*)d_in[4];
  float* y = (float*)d_out;

  char* ws = (char*)d_ws;
  u32* ntp     = (u32*)(ws + 2048);                    // 1 u32
  Tile* tiles  = (Tile*)(ws + 4096);                   // <= 1344 * 16B
  u32* pid_arr = (u32*)(ws + 32768);                   // 65536 u32
  float* glo_a = (float*)(ws + 32768 + 262144);        // 65536 f32
  float* ghi_a = (float*)(ws + 32768 + 2 * 262144);    // 65536 f32
  u32* sorted  = (u32*)(ws + 32768 + 3 * 262144);      // 65536 u32
  u16* WeT     = (u16*)(ws + 32768 + 4 * 262144);      // 524288 bf16 (1MB)
  u32* hist    = (u32*)(ws + 32768 + 4 * 262144 + 1048576);  // 256*256 u32 (256KB)

  k_wt<<<128, 256, 0, stream>>>(We, WeT);
  k_gate<<<256, 256, 0, stream>>>(x, wg, bg, hist, pid_arr, glo_a, ghi_a);
  k_scan<<<1, 256, 0, stream>>>(hist, ntp, tiles);
  k_scatter<<<256, 256, 0, stream>>>(pid_arr, hist, sorted);
  k_moe<<<1144, 256, 0, stream>>>(x, WeT, be, sorted, ntp, tiles, glo_a, ghi_a, y);
}

// Round 3
// 193.847 us; speedup vs baseline: 1.6505x; 1.1217x over previous
//
#include <hip/hip_runtime.h>

typedef unsigned int u32;
typedef unsigned short u16;
typedef float f4 __attribute__((ext_vector_type(4)));
typedef __bf16 b8 __attribute__((ext_vector_type(8)));
typedef unsigned short us8 __attribute__((ext_vector_type(8)));

#define DD 64
#define NE 16
#define OO 512
#define TR 64

struct __align__(16) Tile { u32 pid, slot, nr, pad; };

union U8 { us8 u; b8 b; };

__device__ __forceinline__ u16 f2bf(float f) {
  u32 u = __float_as_uint(f);
  u32 r = (u + 0x7fffu + ((u >> 16) & 1u)) >> 16;
  return (u16)r;
}

// ---------------- We [e][d][o] fp32 -> WeT [e][o][d] bf16 ----------------
__global__ void k_wt(const float* __restrict__ We, u16* __restrict__ WeT) {
  __shared__ float tl[64][65];
  int b = blockIdx.x;          // 16 experts * 8 o-chunks
  int e = b >> 3;
  int oc = (b & 7) * 64;
  int t = threadIdx.x;
  int d = t >> 2, seg = (t & 3) * 16;
  const f4* src = (const f4*)(We + ((size_t)(e * DD + d)) * OO + oc + seg);
  f4 v0 = src[0], v1 = src[1], v2 = src[2], v3 = src[3];
#pragma unroll
  for (int j = 0; j < 4; j++) {
    tl[d][seg + j]      = v0[j];
    tl[d][seg + 4 + j]  = v1[j];
    tl[d][seg + 8 + j]  = v2[j];
    tl[d][seg + 12 + j] = v3[j];
  }
  __syncthreads();
  int o = t >> 2, ds = (t & 3) * 16;
  us8 o0, o1;
#pragma unroll
  for (int j = 0; j < 8; j++) {
    o0[j] = f2bf(tl[ds + j][o]);
    o1[j] = f2bf(tl[ds + 8 + j][o]);
  }
  u16* dst = WeT + ((size_t)(e * OO + oc + o)) * DD + ds;
  *(us8*)dst = o0;
  *(us8*)(dst + 8) = o1;
}

// ---------------- gating: logits -> softmax -> top2; per-block histogram, LDS atomics only ----------------
__global__ void k_gate(const float* __restrict__ x, const float* __restrict__ wg,
                       const float* __restrict__ bg, u32* __restrict__ hist,
                       u32* __restrict__ pid_arr, float* __restrict__ glo_arr,
                       float* __restrict__ ghi_arr) {
  __shared__ u32 hcnt[256];
  int t = threadIdx.x;
  hcnt[t] = 0;
  __syncthreads();
  int row = blockIdx.x * 256 + t;

  float l[NE];
#pragma unroll
  for (int e = 0; e < NE; e++) l[e] = bg[e];

  const f4* xp = (const f4*)(x + (size_t)row * DD);
  for (int d4 = 0; d4 < 16; d4++) {
    f4 xv = xp[d4];
#pragma unroll
    for (int qq = 0; qq < 4; qq++) {
      float xs = xv[qq];
      const float* wrow = wg + (d4 * 4 + qq) * NE;
#pragma unroll
      for (int e = 0; e < NE; e++) l[e] = fmaf(xs, wrow[e], l[e]);
    }
  }
  float mx = l[0];
#pragma unroll
  for (int e = 1; e < NE; e++) mx = fmaxf(mx, l[e]);
  float Z = 0.f;
#pragma unroll
  for (int e = 0; e < NE; e++) Z += __expf(l[e] - mx);
  int i1 = 0; float b1 = l[0];
#pragma unroll
  for (int e = 1; e < NE; e++) { if (l[e] > b1) { b1 = l[e]; i1 = e; } }
  int i2 = -1; float b2 = -1e30f;
#pragma unroll
  for (int e = 0; e < NE; e++) { if (e != i1 && l[e] > b2) { b2 = l[e]; i2 = e; } }
  float p1 = __expf(b1 - mx) / Z;
  float p2 = __expf(b2 - mx) / Z;
  float den = p1 + p2 + 1e-6f;   // reference: top_vals / (sum(top_vals) + 1e-6)
  float g1 = p1 / den, g2 = p2 / den;
  int elo, ehi; float glo, ghi;
  if (i1 < i2) { elo = i1; ehi = i2; glo = g1; ghi = g2; }
  else         { elo = i2; ehi = i1; glo = g2; ghi = g1; }
  u32 pid = (u32)(elo * NE + ehi);
  pid_arr[row] = pid;
  glo_arr[row] = glo;
  ghi_arr[row] = ghi;
  atomicAdd(&hcnt[pid], 1u);   // LDS atomic only
  __syncthreads();
  hist[blockIdx.x * 256 + t] = hcnt[t];   // coalesced, no global atomics
}

// ---------------- per-pid scan over gate-blocks: hist[b][p] -> local exclusive, tot[p] ----------------
__global__ void k_colscan(u32* __restrict__ hist, u32* __restrict__ tot) {
  __shared__ u32 s[256];
  int b = threadIdx.x, p = blockIdx.x;
  u32 v = hist[b * 256 + p];
  s[b] = v;
  __syncthreads();
  for (int d = 1; d < 256; d <<= 1) {
    u32 a = 0;
    if (b >= d) a = s[b - d];
    __syncthreads();
    s[b] += a;
    __syncthreads();
  }
  hist[b * 256 + p] = s[b] - v;   // in-place local exclusive offset
  if (b == 255) tot[p] = s[255];
}

// ---------------- scan totals -> per-pid base + tile descriptors ----------------
__global__ void k_base(const u32* __restrict__ tot, u32* __restrict__ base,
                       u32* __restrict__ ntp, Tile* __restrict__ tiles) {
  __shared__ u32 s[256], s2[256];
  int t = threadIdx.x;
  u32 v = tot[t];
  u32 nt = (v + (TR - 1)) >> 6;
  s[t] = v; s2[t] = nt;
  __syncthreads();
  for (int d = 1; d < 256; d <<= 1) {
    u32 a = 0, c = 0;
    if (t >= d) { a = s[t - d]; c = s2[t - d]; }
    __syncthreads();
    s[t] += a; s2[t] += c;
    __syncthreads();
  }
  u32 rb = s[t] - v;
  u32 tb = s2[t] - nt;
  base[t] = rb;
  for (u32 k = 0; k < nt; k++) {
    Tile td;
    td.pid = (u32)t;
    td.slot = rb + k * (u32)TR;
    u32 rem = v - k * (u32)TR;
    td.nr = rem < (u32)TR ? rem : (u32)TR;
    td.pad = 0;
    tiles[tb + k] = td;
  }
  if (t == 255) *ntp = s2[255];
}

// ---------------- scatter rows into pair buckets (LDS atomics only) ----------------
__global__ void k_scatter(const u32* __restrict__ pid_arr, const u32* __restrict__ hist,
                          const u32* __restrict__ base, u32* __restrict__ sorted) {
  __shared__ u32 lcnt[256], lbase[256];
  int t = threadIdx.x;
  lcnt[t] = 0;
  lbase[t] = base[t];
  __syncthreads();
  int row = blockIdx.x * 256 + t;
  u32 pid = pid_arr[row];
  u32 rank = atomicAdd(&lcnt[pid], 1u);
  u32 off = lbase[pid] + hist[blockIdx.x * 256 + pid];
  sorted[off + rank] = (u32)row;
}

// ---------------- main: per pair-tile GEMM (2 experts) + gated combine ----------------
__global__ void k_moe(const float* __restrict__ x, const u16* __restrict__ WeT,
                      const float* __restrict__ be, const u32* __restrict__ sorted,
                      const u32* __restrict__ ntp, const Tile* __restrict__ tiles,
                      const float* __restrict__ glo_arr, const float* __restrict__ ghi_arr,
                      float* __restrict__ y) {
  __shared__ __align__(16) u16 Xl[TR * 72];     // 9.2 KB, stride 72 breaks conflicts
  __shared__ __align__(16) float Yl[TR * 68];   // 17 KB, stride 68 -> 2-way (free)
  __shared__ u32 rid_s[TR];
  __shared__ float glo_s[TR], ghi_s[TR];

  u32 bid = blockIdx.x;
  if (bid >= *ntp) return;
  Tile td = tiles[bid];
  u32 e_lo = td.pid >> 4, e_hi = td.pid & 15u;
  u32 slot0 = td.slot, nr = td.nr;

  int t = threadIdx.x;
  if (t < TR) {
    u32 i = (u32)t;
    u32 slot = slot0 + ((i < nr) ? i : 0u);
    u32 r = sorted[slot];
    rid_s[t] = r;
    bool valid = i < nr;
    glo_s[t] = valid ? glo_arr[r] : 0.f;
    ghi_s[t] = valid ? ghi_arr[r] : 0.f;
  }
  __syncthreads();
  {
    int i = t >> 2;
    int seg = (t & 3) * 16;
    u32 r = rid_s[i];
    const f4* xp = (const f4*)(x + (size_t)r * DD + seg);
    f4 v0 = xp[0], v1 = xp[1], v2 = xp[2], v3 = xp[3];
    float vv[16] = { v0[0], v0[1], v0[2], v0[3], v1[0], v1[1], v1[2], v1[3],
                     v2[0], v2[1], v2[2], v2[3], v3[0], v3[1], v3[2], v3[3] };
    us8 o0, o1;
#pragma unroll
    for (int j = 0; j < 8; j++) { o0[j] = f2bf(vv[j]); o1[j] = f2bf(vv[8 + j]); }
    *(us8*)&Xl[i * 72 + seg] = o0;
    *(us8*)&Xl[i * 72 + seg + 8] = o1;
  }
  __syncthreads();

  int lane = t & 63;
  int w = t >> 6;
  int q = lane >> 4;      // quad
  int ln = lane & 15;

  // A-fragments: A[m][k], m = ln, k = q*8 + j  (per-MFMA K=32 chunk kc)
  b8 afr[4][2];
#pragma unroll
  for (int mt = 0; mt < 4; mt++)
#pragma unroll
    for (int kc = 0; kc < 2; kc++) {
      U8 tmp; tmp.u = *(const us8*)&Xl[(mt * 16 + ln) * 72 + kc * 32 + q * 8];
      afr[mt][kc] = tmp.b;
    }

  // per-lane gate metadata for the 16 C rows this lane owns (row = mt*16 + q*4 + rr)
  float gl[16], gh[16];
#pragma unroll
  for (int mt = 0; mt < 4; mt++)
#pragma unroll
    for (int rr = 0; rr < 4; rr++) {
      int i = mt * 16 + q * 4 + rr;
      gl[mt * 4 + rr] = glo_s[i];
      gh[mt * 4 + rr] = ghi_s[i];
    }

  const u16* wlo = WeT + (size_t)e_lo * OO * DD;
  const u16* whi = WeT + (size_t)e_hi * OO * DD;
  const f4 zero = {0.f, 0.f, 0.f, 0.f};

  // per jj the block produces one contiguous 64-col stripe: cols [jj*64, jj*64+64)
  for (int jj = 0; jj < 8; jj++) {
    int col = jj * 64 + w * 16 + ln;
    const us8* plo = (const us8*)(wlo + (size_t)col * DD + q * 8);
    const us8* phi = (const us8*)(whi + (size_t)col * DD + q * 8);
    U8 t0, t1, t2, t3;
    t0.u = plo[0]; t1.u = plo[4];   // +32 elems = k-chunk 1
    t2.u = phi[0]; t3.u = phi[4];
    b8 bl0 = t0.b, bl1 = t1.b, bh0 = t2.b, bh1 = t3.b;
    float blo = be[e_lo * OO + col];
    float bhi = be[e_hi * OO + col];

    f4 aL[4], aH[4];
#pragma unroll
    for (int mt = 0; mt < 4; mt++) { aL[mt] = zero; aH[mt] = zero; }
#pragma unroll
    for (int mt = 0; mt < 4; mt++) {
      aL[mt] = __builtin_amdgcn_mfma_f32_16x16x32_bf16(afr[mt][0], bl0, aL[mt], 0, 0, 0);
      aL[mt] = __builtin_amdgcn_mfma_f32_16x16x32_bf16(afr[mt][1], bl1, aL[mt], 0, 0, 0);
      aH[mt] = __builtin_amdgcn_mfma_f32_16x16x32_bf16(afr[mt][0], bh0, aH[mt], 0, 0, 0);
      aH[mt] = __builtin_amdgcn_mfma_f32_16x16x32_bf16(afr[mt][1], bh1, aH[mt], 0, 0, 0);
    }
    // gated combine into the LDS stripe
#pragma unroll
    for (int mt = 0; mt < 4; mt++)
#pragma unroll
      for (int rr = 0; rr < 4; rr++) {
        int i = mt * 16 + q * 4 + rr;
        int idx = mt * 4 + rr;
        float v = gl[idx] * (aL[mt][rr] + blo) + gh[idx] * (aH[mt][rr] + bhi);
        Yl[i * 68 + w * 16 + ln] = v;
      }
    __syncthreads();
    // cooperative store: 8 lanes per row -> 128B contiguous, line-aligned per instruction
    {
      int row0 = t >> 3;          // 0..31
      int c8 = (t & 7) * 4;       // float offset 0..28
#pragma unroll
      for (int half = 0; half < 2; half++) {
        int row = half * 32 + row0;
        if ((u32)row < nr) {
          float* yp = y + (size_t)rid_s[row] * OO + jj * 64;
          const float* sp = &Yl[row * 68];
          *(f4*)(yp + c8)      = *(const f4*)(sp + c8);
          *(f4*)(yp + 32 + c8) = *(const f4*)(sp + 32 + c8);
        }
      }
    }
    __syncthreads();
  }
}

extern "C" void kernel_launch(void* const* d_in, const int* in_sizes, int n_in,
                              void* d_out, int out_size, void* d_ws, size_t ws_size,
                              hipStream_t stream) {
  const float* x  = (const float*)d_in[0];
  const float* wg = (const float*)d_in[1];
  const float* bg = (const float*)d_in[2];
  const float* We = (const float*)d_in[3];
  const float* be = (const float*)d_in[4];
  float* y = (float*)d_out;

  char* ws = (char*)d_ws;
  u32* ntp     = (u32*)(ws + 0);                       // 1 u32
  Tile* tiles  = (Tile*)(ws + 4096);                   // <= 1344 * 16B
  u32* pid_arr = (u32*)(ws + 32768);                   // 65536 u32
  float* glo_a = (float*)(ws + 32768 + 262144);        // 65536 f32
  float* ghi_a = (float*)(ws + 32768 + 2 * 262144);    // 65536 f32
  u32* sorted  = (u32*)(ws + 32768 + 3 * 262144);      // 65536 u32
  u16* WeT     = (u16*)(ws + 32768 + 4 * 262144);      // 524288 bf16 (1MB)
  u32* hist    = (u32*)(ws + 32768 + 4 * 262144 + 1048576);            // 256*256 u32
  u32* tot     = (u32*)(ws + 32768 + 4 * 262144 + 1048576 + 262144);   // 256 u32
  u32* base    = (u32*)(ws + 32768 + 4 * 262144 + 1048576 + 262144 + 1024); // 256 u32

  k_wt<<<128, 256, 0, stream>>>(We, WeT);
  k_gate<<<256, 256, 0, stream>>>(x, wg, bg, hist, pid_arr, glo_a, ghi_a);
  k_colscan<<<256, 256, 0, stream>>>(hist, tot);
  k_base<<<1, 256, 0, stream>>>(tot, base, ntp, tiles);
  k_scatter<<<256, 256, 0, stream>>>(pid_arr, hist, base, sorted);
  k_moe<<<1144, 256, 0, stream>>>(x, WeT, be, sorted, ntp, tiles, glo_a, ghi_a, y);
}